// Round 8
// baseline (300.976 us; speedup 1.0000x reference)
//
#include <hip/hip_runtime.h>

#define LOG2E 1.44269504088896340736f

typedef short    short8  __attribute__((ext_vector_type(8)));
typedef float    floatx4 __attribute__((ext_vector_type(4)));
typedef unsigned uintx4  __attribute__((ext_vector_type(4)));

__device__ __forceinline__ unsigned pk_bf16(float lo, float hi) {
    unsigned r;
    asm("v_cvt_pk_bf16_f32 %0, %1, %2" : "=v"(r) : "v"(lo), "v"(hi));
    return r;
}
__device__ __forceinline__ float sigm(float v) {
    return __builtin_amdgcn_rcpf(1.0f + __builtin_amdgcn_exp2f(-LOG2E * v));
}
__device__ __forceinline__ float tanhx(float v) {
    return 1.0f - 2.0f * __builtin_amdgcn_rcpf(1.0f + __builtin_amdgcn_exp2f(2.0f * LOG2E * v));
}

// One-barrier MFMA LSTM. Grid 256 x 256 threads (4 waves), block owns 8 batches.
// Orientation: gates[g, m] = W_hh[g,:] @ h[:, m]  (A = W constant in regs, B = h).
// Wave U computes M-tiles {g in [64*tau + 16*U, +16), tau=0..3}:
//   C/D layout (col=lane&15=batch m, row=4*(lane>>4)+r = u offset) puts ALL FOUR
//   gate types for (m=l15, u=16U+4lq+r) in lane registers -> c/h update is
//   register-local. Single barrier per step with double-buffered h in LDS.
// x-projection + bias ride in as the MFMA C-input (computed during ds waits).
__global__ void __launch_bounds__(256, 1)
lstm_mfma(const float* __restrict__ x,      // [2048,512]
          const float* __restrict__ W_ih,   // [256]
          const float* __restrict__ W_hh,   // [256,64]
          const float* __restrict__ b_ih,   // [256]
          const float* __restrict__ b_hh,   // [256]
          const float* __restrict__ W_fc,   // [2,64]
          const float* __restrict__ b_fc,   // [2]
          float* __restrict__ out)          // [2048,2]
{
    __shared__ unsigned hlds[2 * 16 * 32];  // 2 buffers: 16 rows(batch) x 64 bf16(u)
    __shared__ float    red[4][8][2];       // FC cross-wave reduce

    const int tid  = threadIdx.x;
    const int U    = tid >> 6;              // wave 0..3 (u-block)
    const int lane = tid & 63;
    const int l15  = lane & 15;             // batch m (8 real, 8 pad)
    const int lq   = lane >> 4;
    const int b0   = blockIdx.x * 8;

    // zero both h buffers (pad rows 8-15 stay zero forever)
    #pragma unroll
    for (int i = 0; i < 4; ++i) hlds[tid + 256 * i] = 0u;

    // ---- A fragments: W_hh rows, bf16. lane: row=l15 (within tile), k=32f+8lq+e ----
    short8 wfrag[4][2];
    #pragma unroll
    for (int t4 = 0; t4 < 4; ++t4) {
        const int grow = t4 * 64 + U * 16 + l15;
        #pragma unroll
        for (int f = 0; f < 2; ++f) {
            const float* p = W_hh + grow * 64 + 32 * f + 8 * lq;
            uintx4 uv;
            uv.x = pk_bf16(p[0], p[1]);
            uv.y = pk_bf16(p[2], p[3]);
            uv.z = pk_bf16(p[4], p[5]);
            uv.w = pk_bf16(p[6], p[7]);
            wfrag[t4][f] = __builtin_bit_cast(short8, uv);
        }
    }
    // ---- per-lane gate constants for (tau, r): g = 64*tau + 16U + 4lq + r ----
    float wih[4][4], bias[4][4];
    #pragma unroll
    for (int t4 = 0; t4 < 4; ++t4)
        #pragma unroll
        for (int r = 0; r < 4; ++r) {
            const int g = t4 * 64 + U * 16 + 4 * lq + r;
            wih[t4][r]  = W_ih[g];
            bias[t4][r] = b_ih[g] + b_hh[g];
        }

    // ---- LDS addressing (word-index XOR swizzle, validated in R6) ----
    const int swz = (l15 & 7) << 2;
    const uintx4* rd00 = (const uintx4*)&hlds[      l15 * 32 + (( 0 + 4 * lq) ^ swz)];
    const uintx4* rd01 = (const uintx4*)&hlds[      l15 * 32 + ((16 + 4 * lq) ^ swz)];
    const uintx4* rd10 = (const uintx4*)&hlds[512 + l15 * 32 + (( 0 + 4 * lq) ^ swz)];
    const uintx4* rd11 = (const uintx4*)&hlds[512 + l15 * 32 + ((16 + 4 * lq) ^ swz)];
    unsigned* wr0 = &hlds[      l15 * 32 + ((8 * U + 2 * lq) ^ swz)];
    unsigned* wr1 = &hlds[512 + l15 * 32 + ((8 * U + 2 * lq) ^ swz)];

    float c[4]  = {0.f, 0.f, 0.f, 0.f};
    float hq[4] = {0.f, 0.f, 0.f, 0.f};

    const float* xrow = x + (long)(b0 + (l15 & 7)) * 512;
    float xv = xrow[0];                      // current-step x (prefetched)

    __syncthreads();

#define STEP(RD0, RD1, WRP, T) do {                                              \
    const int   tn  = ((T) < 511) ? (T) + 1 : 511;                               \
    const float xnv = xrow[tn];              /* prefetch next step's x */        \
    floatx4 cin[4];                                                              \
    _Pragma("unroll")                                                            \
    for (int t4 = 0; t4 < 4; ++t4)                                               \
        _Pragma("unroll")                                                        \
        for (int r = 0; r < 4; ++r)                                              \
            cin[t4][r] = fmaf(xv, wih[t4][r], bias[t4][r]);                      \
    short8 hb0 = __builtin_bit_cast(short8, *(RD0));                             \
    short8 hb1 = __builtin_bit_cast(short8, *(RD1));                             \
    floatx4 acc[4];                                                              \
    _Pragma("unroll")                                                            \
    for (int t4 = 0; t4 < 4; ++t4) {                                             \
        acc[t4] = __builtin_amdgcn_mfma_f32_16x16x32_bf16(wfrag[t4][0], hb0,     \
                                                          cin[t4], 0, 0, 0);     \
        acc[t4] = __builtin_amdgcn_mfma_f32_16x16x32_bf16(wfrag[t4][1], hb1,     \
                                                          acc[t4], 0, 0, 0);     \
    }                                                                            \
    _Pragma("unroll")                                                            \
    for (int r = 0; r < 4; ++r) {                                                \
        const float ig = sigm(acc[0][r]);                                        \
        const float fg = sigm(acc[1][r]);                                        \
        const float gg = tanhx(acc[2][r]);                                       \
        const float og = sigm(acc[3][r]);                                        \
        c[r]  = fmaf(fg, c[r], ig * gg);                                         \
        hq[r] = og * tanhx(c[r]);                                                \
    }                                                                            \
    if (l15 < 8) {                                                               \
        uint2 pk;                                                                \
        pk.x = pk_bf16(hq[0], hq[1]);                                            \
        pk.y = pk_bf16(hq[2], hq[3]);                                            \
        *(uint2*)(WRP) = pk;                                                     \
    }                                                                            \
    xv = xnv;                                                                    \
    __syncthreads();                                                             \
} while (0)

    for (int t2 = 0; t2 < 512; t2 += 2) {
        STEP(rd00, rd01, wr1, t2);       // read buf0 (h(t-1)), write buf1
        STEP(rd10, rd11, wr0, t2 + 1);   // read buf1,           write buf0
    }
#undef STEP

    // ---- epilogue: out[b0+m,:] = h_T[m,:] @ W_fc.T + b_fc ----
    float p0 = 0.f, p1 = 0.f;
    #pragma unroll
    for (int r = 0; r < 4; ++r) {
        const int u = U * 16 + 4 * lq + r;
        p0 = fmaf(hq[r], W_fc[u],      p0);
        p1 = fmaf(hq[r], W_fc[64 + u], p1);
    }
    // reduce over lq (lanes l15, l15+16, l15+32, l15+48)
    p0 += __shfl_down(p0, 32);  p0 += __shfl_down(p0, 16);
    p1 += __shfl_down(p1, 32);  p1 += __shfl_down(p1, 16);
    if (lane < 8) { red[U][lane][0] = p0; red[U][lane][1] = p1; }
    __syncthreads();
    if (tid < 16) {
        const int m = tid >> 1, cls = tid & 1;
        const float s = red[0][m][cls] + red[1][m][cls] +
                        red[2][m][cls] + red[3][m][cls] + b_fc[cls];
        out[(b0 + m) * 2 + cls] = s;
    }
}

extern "C" void kernel_launch(void* const* d_in, const int* in_sizes, int n_in,
                              void* d_out, int out_size, void* d_ws, size_t ws_size,
                              hipStream_t stream) {
    const float* x    = (const float*)d_in[0];
    const float* W_ih = (const float*)d_in[1];
    const float* W_hh = (const float*)d_in[2];
    const float* b_ih = (const float*)d_in[3];
    const float* b_hh = (const float*)d_in[4];
    const float* W_fc = (const float*)d_in[5];
    const float* b_fc = (const float*)d_in[6];
    float* out = (float*)d_out;

    dim3 grid(256);    // 8 batches per block -> 1 block per CU
    dim3 block(256);   // 4 waves
    hipLaunchKernelGGL(lstm_mfma, grid, block, 0, stream,
                       x, W_ih, W_hh, b_ih, b_hh, W_fc, b_fc, out);
}